// Round 12
// baseline (81.119 us; speedup 1.0000x reference)
//
#include <hip/hip_runtime.h>

typedef float  f32x4  __attribute__((ext_vector_type(4)));
typedef short  s16x8  __attribute__((ext_vector_type(8)));
typedef short  s16x4  __attribute__((ext_vector_type(4)));

__device__ __forceinline__ unsigned short f2bf(float f) {
    unsigned int u = __float_as_uint(f);
    return (unsigned short)((u + 0x7FFFu + ((u >> 16) & 1u)) >> 16);
}

__device__ __forceinline__ s16x8 cvt8(f32x4 a, f32x4 b) {
    union { unsigned int u[4]; s16x8 v; } r;
    asm("v_cvt_pk_bf16_f32 %0, %1, %2" : "=v"(r.u[0]) : "v"(a[0]), "v"(a[1]));
    asm("v_cvt_pk_bf16_f32 %0, %1, %2" : "=v"(r.u[1]) : "v"(a[2]), "v"(a[3]));
    asm("v_cvt_pk_bf16_f32 %0, %1, %2" : "=v"(r.u[2]) : "v"(b[0]), "v"(b[1]));
    asm("v_cvt_pk_bf16_f32 %0, %1, %2" : "=v"(r.u[3]) : "v"(b[2]), "v"(b[3]));
    return r.v;
}

// lgkm-only barrier (vmcnt stays in flight)
__device__ __forceinline__ void lds_barrier() {
    asm volatile("s_waitcnt lgkmcnt(0)" ::: "memory");
    __builtin_amdgcn_s_barrier();
    asm volatile("" ::: "memory");
}

// ---------------------------------------------------------------------------
// Kernel 0: wt3 = FRAGMENT-MAJOR bf16 weights (verified R9/R11).
// Fragment (n16,ks,kkk) = one wave's exact MFMA B-operand (64 lanes x 16B):
// value = W_sel[k][n&127], n = n16*16 + (lane&15),
// k = ks*64 + kkk*32 + (lane>>4)*8 + j; byte = fragid*1024 + lane*16 + j*2.
// ---------------------------------------------------------------------------
__global__ void prep_wt(const float* __restrict__ Wq,
                        const float* __restrict__ Wk,
                        const float* __restrict__ Wv,
                        unsigned char* __restrict__ wt3) {
    int n = blockIdx.x;                       // 0..383
    const float* W = (n < 128) ? Wq : ((n < 256) ? Wk : Wv);
    int h = n & 127;
    int n16 = n >> 4, lmn = n & 15;
    for (int k = threadIdx.x; k < 1024; k += blockDim.x) {
        unsigned short v = f2bf(W[(size_t)k * 128 + h]);
        int ks = k >> 6, rem = k & 63;
        int kkk = rem >> 5, l4_ = (rem >> 3) & 3, j = rem & 7;
        int lane = l4_ * 16 + lmn;
        size_t off = (size_t)(n16 * 32 + ks * 2 + kkk) * 1024 + lane * 16 + j * 2;
        *(unsigned short*)(wt3 + off) = v;
    }
}

// ---------------------------------------------------------------------------
// Kernel 1: QKV GEMM — OCCUPANCY play: 16 waves/block (1024 thr), grid 256,
// 4 waves/SIMD (vs 2 in every BM=128 round so far).  BM=128, BN=384 (x read
// once).  Wave tile 64x48: acc[4][3]=48 VGPR; B wave-private regs from
// fragment-major wt3 (compiler-counted waits, zero manual vmcnt); A-only
// LDS 2x16KB swizzled dbuf, ONE lgkm-only barrier/tile.  af read 2-at-a-time
// and JIT kkk1 B-loads keep VGPR ~120 <= 128 (launch_bounds(1024,4)).
// Latency story per tile: bqE1 issued at tile start, consumed after
// MFMA(bqE0) (~300cy cover); bqO0 issued mid-tile, consumed next tile.
// Outputs: Q,K bf16 [B*T][128]; V transposed bf16 [B][128][256].
// ---------------------------------------------------------------------------
__global__ __launch_bounds__(1024, 4) void qkv_gemm(
    const float* __restrict__ x,
    const unsigned char* __restrict__ wt3,
    unsigned short* __restrict__ qo,
    unsigned short* __restrict__ ko,
    unsigned short* __restrict__ vto) {

    __shared__ char smem[32768];              // A: 2 x [128][128B] swizzled

    const int tid = threadIdx.x;
    const int bm  = blockIdx.x;               // 0..255 (M tiles of 128)
    const int lane = tid & 63, wid = tid >> 6;
    const int lm = lane & 15, l4 = lane >> 4;
    const int wn = wid & 7;                   // N group (48 cols)
    const int wm = wid >> 3;                  // M half (64 rows)

    f32x4 acc[4][3];
#pragma unroll
    for (int i = 0; i < 4; ++i)
#pragma unroll
        for (int j = 0; j < 3; ++j) acc[i][j] = (f32x4)0.f;

    // ---- A staging: thread -> row tid>>3, 8 consecutive f32 ----
    const int ar  = tid >> 3;                 // 0..127
    const int ac8 = tid & 7;
    const float* xp = x + (size_t)(bm * 128 + ar) * 1024 + ac8 * 8;
    const int aw = ar * 128 + ((ac8 << 4) ^ ((ar & 7) << 4));

    // ---- B fragment base (wave-private; frag fi = wn*3+ni) ----
    const unsigned char* wb = wt3 + (size_t)(wn * 3) * 32768 + (size_t)lane * 16;
    // byte offset for (ni, t, kkk): ni*32768 + t*2048 + kkk*1024

    int arow[4];
#pragma unroll
    for (int mi = 0; mi < 4; ++mi) arow[mi] = wm * 64 + mi * 16 + lm;

    s16x8 bqE0[3], bqE1[3], bqO0[3], bqO1[3];
    f32x4 pa0, pa1;

#define MFMA_HALF(AB, KOFF, BQ)                                                \
    do {                                                                       \
        s16x8 af0 = *(const s16x8*)(smem + (AB) + arow[0] * 128 +              \
                     (((KOFF) + l4 * 16) ^ ((arow[0] & 7) << 4)));             \
        s16x8 af1 = *(const s16x8*)(smem + (AB) + arow[1] * 128 +              \
                     (((KOFF) + l4 * 16) ^ ((arow[1] & 7) << 4)));             \
        _Pragma("unroll")                                                      \
        for (int ni = 0; ni < 3; ++ni) {                                       \
            acc[0][ni] = __builtin_amdgcn_mfma_f32_16x16x32_bf16(              \
                af0, (BQ)[ni], acc[0][ni], 0, 0, 0);                           \
            acc[1][ni] = __builtin_amdgcn_mfma_f32_16x16x32_bf16(              \
                af1, (BQ)[ni], acc[1][ni], 0, 0, 0);                           \
        }                                                                      \
        s16x8 af2 = *(const s16x8*)(smem + (AB) + arow[2] * 128 +              \
                     (((KOFF) + l4 * 16) ^ ((arow[2] & 7) << 4)));             \
        s16x8 af3 = *(const s16x8*)(smem + (AB) + arow[3] * 128 +              \
                     (((KOFF) + l4 * 16) ^ ((arow[3] & 7) << 4)));             \
        _Pragma("unroll")                                                      \
        for (int ni = 0; ni < 3; ++ni) {                                       \
            acc[2][ni] = __builtin_amdgcn_mfma_f32_16x16x32_bf16(              \
                af2, (BQ)[ni], acc[2][ni], 0, 0, 0);                           \
            acc[3][ni] = __builtin_amdgcn_mfma_f32_16x16x32_bf16(              \
                af3, (BQ)[ni], acc[3][ni], 0, 0, 0);                           \
        }                                                                      \
    } while (0)

#define BLOAD(DST, T, KKK)                                                     \
    do {                                                                       \
        _Pragma("unroll")                                                      \
        for (int ni = 0; ni < 3; ++ni)                                         \
            (DST)[ni] = *(const s16x8*)(wb + ni * 32768 + (T) * 2048 +         \
                                        (KKK) * 1024);                         \
    } while (0)

    // ---- prologue: stage A(0), load B(0,kkk0), pa=A(1) ----
    {
        f32x4 a0 = *(const f32x4*)(xp);
        f32x4 a1 = *(const f32x4*)(xp + 4);
        BLOAD(bqE0, 0, 0);
        *(s16x8*)(smem + aw) = cvt8(a0, a1);
        pa0 = *(const f32x4*)(xp + 64);
        pa1 = *(const f32x4*)(xp + 68);
        lds_barrier();
    }

    for (int tp = 0; tp < 8; ++tp) {
        const int t = tp * 2;
        // ============ EVEN tile t (A buf0) ============
        BLOAD(bqE1, t, 1);                    // used after MFMA(bqE0): covered
        MFMA_HALF(0, 0, bqE0);
        BLOAD(bqO0, t + 1, 0);                // used next tile
        MFMA_HALF(0, 64, bqE1);
        // stage A(t+1) -> buf1; pa = A(t+2)
        *(s16x8*)(smem + 16384 + aw) = cvt8(pa0, pa1);
        if (tp < 7 || true) {
            const float* xq = xp + (t + 2) * 64;
            if (t + 2 < 16) {
                pa0 = *(const f32x4*)(xq);
                pa1 = *(const f32x4*)(xq + 4);
            }
        }
        lds_barrier();

        // ============ ODD tile t+1 (A buf1) ============
        BLOAD(bqO1, t + 1, 1);
        MFMA_HALF(16384, 0, bqO0);
        if (tp < 7) BLOAD(bqE0, t + 2, 0);
        MFMA_HALF(16384, 64, bqO1);
        if (tp < 7) {
            *(s16x8*)(smem + aw) = cvt8(pa0, pa1);
            const float* xq = xp + (t + 3) * 64;
            pa0 = *(const f32x4*)(xq);
            pa1 = *(const f32x4*)(xq + 4);
            lds_barrier();
        }
    }

#undef MFMA_HALF
#undef BLOAD

    // ---- epilogue (layout verified R6-R11) ----
#pragma unroll
    for (int mi = 0; mi < 4; ++mi) {
        int m0 = bm * 128 + wm * 64 + mi * 16 + l4 * 4;  // j adds 0..3
#pragma unroll
        for (int ni = 0; ni < 3; ++ni) {
            int nb  = wn * 48 + ni * 16;
            int mat = nb >> 7;                 // 0=Q 1=K 2=V
            int col = (nb & 127) + lm;
            if (mat == 2) {
                int bb2 = m0 >> 8, tt = m0 & 255;
                s16x4 w4;
#pragma unroll
                for (int j = 0; j < 4; ++j) w4[j] = (short)f2bf(acc[mi][ni][j]);
                *(s16x4*)(vto + ((size_t)bb2 * 128 + col) * 256 + tt) = w4;
            } else {
                unsigned short* dst = (mat == 0) ? qo : ko;
#pragma unroll
                for (int j = 0; j < 4; ++j)
                    dst[(size_t)(m0 + j) * 128 + col] = f2bf(acc[mi][ni][j]);
            }
        }
    }
}

// ---------------------------------------------------------------------------
// Kernel 2: causal attention (unchanged, verified; ~7µs).
// ---------------------------------------------------------------------------
__global__ __launch_bounds__(512) void attn(
    const unsigned short* __restrict__ q,
    const unsigned short* __restrict__ k,
    const unsigned short* __restrict__ vt,
    float* __restrict__ out) {

    __shared__ char pbuf[65536];               // 8 waves x [16][256] bf16

    const int tid = threadIdx.x, wid = tid >> 6, lane = tid & 63;
    const int lm = lane & 15, l4 = lane >> 4;
    const int b = blockIdx.x >> 1, qt = blockIdx.x & 1;
    const int qbase = qt << 7;
    const int t0 = qbase + wid * 16;
    const int nfrags = (qbase + 128) >> 4;
    const int nkf    = (qbase + 128) >> 5;

    const unsigned short* qrow = q + (size_t)(b * 256 + t0 + lm) * 128 + l4 * 8;
    s16x8 qf[4];
#pragma unroll
    for (int kf = 0; kf < 4; ++kf) qf[kf] = *(const s16x8*)(qrow + kf * 32);

    f32x4 sacc[16];
#pragma unroll
    for (int i = 0; i < 16; ++i) sacc[i] = (f32x4)0.f;

    const unsigned short* kbase = k + (size_t)(b * 256) * 128 + l4 * 8;
#pragma unroll
    for (int nf = 0; nf < 16; ++nf) {
        if (nf < nfrags) {
#pragma unroll
            for (int kf = 0; kf < 4; ++kf) {
                s16x8 a = *(const s16x8*)(kbase + (size_t)(nf * 16 + lm) * 128 + kf * 32);
                sacc[nf] = __builtin_amdgcn_mfma_f32_16x16x32_bf16(a, qf[kf], sacc[nf], 0, 0, 0);
            }
        }
    }

    const float scale = 0.08838834764831845f;  // 1/sqrt(128)
    const int tg = t0 + lm;
    float mx = -1e30f;
#pragma unroll
    for (int nf = 0; nf < 16; ++nf) {
        if (nf < nfrags) {
#pragma unroll
            for (int j = 0; j < 4; ++j) {
                int kv = nf * 16 + l4 * 4 + j;
                float s = sacc[nf][j] * scale;
                s = (kv > tg) ? -1e30f : s;
                sacc[nf][j] = s;
                mx = fmaxf(mx, s);
            }
        }
    }
    mx = fmaxf(mx, __shfl_xor(mx, 16));
    mx = fmaxf(mx, __shfl_xor(mx, 32));
    float sum = 0.f;
#pragma unroll
    for (int nf = 0; nf < 16; ++nf) {
        if (nf < nfrags) {
#pragma unroll
            for (int j = 0; j < 4; ++j) {
                float p = __expf(sacc[nf][j] - mx);
                sacc[nf][j] = p;
                sum += p;
            }
        }
    }
    sum += __shfl_xor(sum, 16);
    sum += __shfl_xor(sum, 32);
    float rinv = 1.0f / sum;

    char* pw = pbuf + wid * 8192 + lm * 512;
#pragma unroll
    for (int nf = 0; nf < 16; ++nf) {
        if (nf < nfrags) {
            s16x4 w;
#pragma unroll
            for (int j = 0; j < 4; ++j) w[j] = (short)f2bf(sacc[nf][j] * rinv);
            *(s16x4*)(pw + ((nf * 32 + l4 * 8) ^ ((lm & 7) << 4))) = w;
        }
    }
    asm volatile("s_waitcnt lgkmcnt(0)" ::: "memory");

    f32x4 oacc[8];
#pragma unroll
    for (int i = 0; i < 8; ++i) oacc[i] = (f32x4)0.f;

    const unsigned short* vbase = vt + (size_t)b * 32768 + l4 * 8;
#pragma unroll
    for (int kvf = 0; kvf < 8; ++kvf) {
        if (kvf < nkf) {
            s16x8 pf = *(const s16x8*)(pbuf + wid * 8192 + lm * 512 +
                        ((kvf * 64 + l4 * 16) ^ ((lm & 7) << 4)));
#pragma unroll
            for (int hf = 0; hf < 8; ++hf) {
                s16x8 a = *(const s16x8*)(vbase + (size_t)(hf * 16 + lm) * 256 + kvf * 32);
                oacc[hf] = __builtin_amdgcn_mfma_f32_16x16x32_bf16(a, pf, oacc[hf], 0, 0, 0);
            }
        }
    }

    float* ob = out + (size_t)(b * 256 + t0 + lm) * 128 + l4 * 4;
#pragma unroll
    for (int hf = 0; hf < 8; ++hf)
        *(f32x4*)(ob + hf * 16) = oacc[hf];
}

// ---------------------------------------------------------------------------
extern "C" void kernel_launch(void* const* d_in, const int* in_sizes, int n_in,
                              void* d_out, int out_size, void* d_ws, size_t ws_size,
                              hipStream_t stream) {
    const float* x  = (const float*)d_in[0];
    const float* Wq = (const float*)d_in[1];
    const float* Wk = (const float*)d_in[2];
    const float* Wv = (const float*)d_in[3];
    float* out = (float*)d_out;

    char* ws = (char*)d_ws;
    unsigned char*  wt = (unsigned char*)(ws);                     // 786432 B (fragment-major)
    unsigned short* qb = (unsigned short*)(ws + 786432);
    unsigned short* kb = (unsigned short*)(ws + 786432 + 8388608);
    unsigned short* vb = (unsigned short*)(ws + 786432 + 2 * 8388608);

    prep_wt<<<384, 256, 0, stream>>>(Wq, Wk, Wv, wt);
    qkv_gemm<<<256, 1024, 0, stream>>>(x, wt, qb, kb, vb);
    attn<<<256, 512, 0, stream>>>(qb, kb, vb, out);
}